// Round 8
// baseline (237.709 us; speedup 1.0000x reference)
//
#include <hip/hip_runtime.h>

#pragma clang fp contract(off)

typedef unsigned int u32;
typedef unsigned long long u64;
typedef long long i64;

#define N_ROWS 32768
#define NCLS 81
#define TOPK 4096
#define EQCAP 8192
#define IMGW_M1 1332.0f
#define IMGH_M1 799.0f

// k_cand geometry: 8 threads/row, 32 rows/block, 1024 blocks
#define CAND_THREADS 256
#define RPB 32
#define CAND_GRID (N_ROWS / RPB)          // 1024
#define CPT 11
#define REG_CAP 640                       // per-block region; hard bound 608 (19/row max)
#define ROW_F4 ((RPB * NCLS) / 4)         // 648 float4 per block slice (exactly)

// level-1 bins: f32 bits of p in (0.05, 1.0] -> hi16 in [0x3D4C, 0x3F80]
#define H1_BASE 0x3D4Cu
#define H1_BINS 576
#define HIST1_GRID 64
#define REGS_PER_H1 (CAND_GRID / HIST1_GRID)  // 16

#define COLL_GRID 512
#define COLL_CAP 1280                     // 2 regions * 640

// ---------------- ws layout (u32 units) ----------------
// cnt[16]: 1=selCount 2=eqCount 5=cutKey 6=numFromEqual  (1,2 zeroed by k_mid)
// hist1p[64*576]   atomic-free partial level-1 hists
// candCnt[1024]    per-region candidate counts
// candKey[1024*640], candIdx[1024*640]
// sel u64[4096], eqI[8192], rboxes[4096*4], rvals[4096], rlabel[4096]

// fast f64 exp for d <= 0 (clamped at -45). Cody-Waite + Taylor-13.
// Relative error ~3e-16 — decisions have >= f32-ulp (6e-8) margins.
__device__ inline double fast_exp_neg(double d) {
    if (d < -45.0) return 0.0;
    const double L2E    = 1.4426950408889634074;
    const double LN2_HI = 6.93147180369123816490e-01;
    const double LN2_LO = 1.90821492927058770002e-10;
    double n = __builtin_rint(d * L2E);
    double r = __builtin_fma(-n, LN2_HI, d);
    r = __builtin_fma(-n, LN2_LO, r);
    double p = 1.0 / 6227020800.0;
    p = __builtin_fma(p, r, 1.0 / 479001600.0);
    p = __builtin_fma(p, r, 1.0 / 39916800.0);
    p = __builtin_fma(p, r, 1.0 / 3628800.0);
    p = __builtin_fma(p, r, 1.0 / 362880.0);
    p = __builtin_fma(p, r, 1.0 / 40320.0);
    p = __builtin_fma(p, r, 1.0 / 5040.0);
    p = __builtin_fma(p, r, 1.0 / 720.0);
    p = __builtin_fma(p, r, 1.0 / 120.0);
    p = __builtin_fma(p, r, 1.0 / 24.0);
    p = __builtin_fma(p, r, 1.0 / 6.0);
    p = __builtin_fma(p, r, 0.5);
    p = __builtin_fma(p, r, 1.0);
    p = __builtin_fma(p, r, 1.0);
    i64 ni = (i64)n;
    double sc = __longlong_as_double((i64)(1023 + ni) << 52);
    return p * sc;
}

// softmax + threshold + compaction into PER-BLOCK region (no global atomics).
// Arithmetic order identical to the passing R7 kernel -> bit-identical decisions.
__global__ void __launch_bounds__(256) k_cand(const float* __restrict__ x,
                                              u32* __restrict__ candKey,
                                              u32* __restrict__ candIdx,
                                              u32* __restrict__ candCnt) {
    __shared__ float4 lx4[ROW_F4];
    __shared__ u32 lK[REG_CAP];
    __shared__ u32 lI[REG_CAP];
    __shared__ u32 lcnt;
    float* lx = (float*)lx4;
    const int t = threadIdx.x;
    if (t == 0) lcnt = 0;

    const float4* xv = (const float4*)x + (size_t)blockIdx.x * ROW_F4;
    for (int i = t; i < ROW_F4; i += CAND_THREADS) lx4[i] = xv[i];
    __syncthreads();

    const int rl = t >> 3;
    const int q = t & 7;
    const int c0 = q * 10;
    const int cEff = (q == 7) ? 11 : 10;
    const int row = blockIdx.x * RPB + rl;
    const float* xr = lx + rl * NCLS;

    float v[CPT];
    #pragma unroll
    for (int i = 0; i < CPT; i++) v[i] = (i < cEff) ? xr[c0 + i] : -1.0e30f;

    float m = v[0];
    #pragma unroll
    for (int i = 1; i < CPT; i++) m = fmaxf(m, v[i]);
    m = fmaxf(m, __shfl_xor(m, 1));
    m = fmaxf(m, __shfl_xor(m, 2));
    m = fmaxf(m, __shfl_xor(m, 4));

    double s = 0.0;
    #pragma unroll
    for (int i = 0; i < CPT; i++) {
        if (i < cEff) {
            float d = v[i] - m;
            s += fast_exp_neg((double)d);
        }
    }
    s += __shfl_xor(s, 1);
    s += __shfl_xor(s, 2);
    s += __shfl_xor(s, 4);

    const double THRMID = (double)0.05f + 0x1.0p-29;
    double ethr = THRMID * s;
    #pragma unroll
    for (int i = 0; i < CPT; i++) {
        int c = c0 + i;
        if (i < cEff && c != 0) {
            float d = v[i] - m;
            double e = fast_exp_neg((double)d);
            if (e > ethr) {
                float pf = (float)(e / s);
                u32 slot = atomicAdd(&lcnt, 1u);
                lK[slot] = __float_as_uint(pf);
                lI[slot] = (u32)(row * NCLS + c);
            }
        }
    }
    __syncthreads();
    u32 tot = lcnt;                   // <= 608 mathematically
    if (t == 0) candCnt[blockIdx.x] = tot;
    u32 base = blockIdx.x * REG_CAP;
    for (u32 i = t; i < tot; i += CAND_THREADS) {
        candKey[base + i] = lK[i];
        candIdx[base + i] = lI[i];
    }
}

// atomic-free level-1 partial histograms: block b covers 16 regions,
// writes its full 576-word slice (no pre-zero needed anywhere).
__global__ void __launch_bounds__(256) k_hist1(const u32* __restrict__ candKey,
                                               const u32* __restrict__ candCnt,
                                               u32* __restrict__ hist1p) {
    __shared__ u32 lh[H1_BINS];
    int t = threadIdx.x;
    for (int i = t; i < H1_BINS; i += 256) lh[i] = 0;
    __syncthreads();
    u32 r0 = blockIdx.x * REGS_PER_H1;
    for (u32 reg = r0; reg < r0 + REGS_PER_H1; reg++) {
        u32 n = candCnt[reg]; if (n > REG_CAP) n = REG_CAP;
        const u32* kp = candKey + reg * REG_CAP;
        for (u32 i = t; i < n; i += 256) {
            u32 b = (kp[i] >> 16) - H1_BASE;
            if (b < (u32)H1_BINS) atomicAdd(&lh[b], 1u);
        }
    }
    __syncthreads();
    u32 ob = blockIdx.x * H1_BINS;
    for (int i = t; i < H1_BINS; i += 256) hist1p[ob + i] = lh[i];
}

// fused cutoff finder, all-LDS: level-1 (sum partials + suffix scan) ->
// level-2 bits[15:4] (4096-bin LDS hist via coalesced candidate rescan) ->
// level-3 bits[3:0] (16-bin). Also zeroes cnt[1]/cnt[2] for k_collect.
__global__ void __launch_bounds__(1024) k_mid(const u32* __restrict__ candKey,
                                              const u32* __restrict__ candCnt,
                                              u32* __restrict__ cnt) {
    __shared__ u32 cs[1024];
    __shared__ u32 h2[4096];
    __shared__ u32 h3[16];
    __shared__ u32 sB, sAcc, sB2, sAcc2, sFound;
    int t = threadIdx.x;
    const int wave = t >> 6, lane = t & 63;
    if (t == 0) sFound = 0;
    if (t == 1) { cnt[1] = 0; cnt[2] = 0; }
    // level-1: sum 64 partials per bin (coalesced across lanes)
    u32 s1 = 0;
    if (t < H1_BINS) {
        for (int j = 0; j < HIST1_GRID; j++) s1 += __ldg(&((const u32*)candCnt - 0)[0]) * 0u; // no-op keep simple
    }
    s1 = 0;
    if (t < H1_BINS) {
        const u32* hp = /* hist1p passed via candCnt+? no */ nullptr; (void)hp;
    }
    // (see below: hist1p pointer passed separately)
    cs[t] = 0;
    __syncthreads();
    (void)s1; (void)wave; (void)lane; (void)sB; (void)sAcc; (void)sB2; (void)sAcc2; (void)sFound;
    (void)h2; (void)h3; (void)cs; (void)candKey; (void)cnt;
}

// real k_mid (the stub above is unused; kept minimal to avoid accidental use)
__global__ void __launch_bounds__(1024) k_mid2(const u32* __restrict__ candKey,
                                               const u32* __restrict__ candCnt,
                                               const u32* __restrict__ hist1p,
                                               u32* __restrict__ cnt) {
    __shared__ u32 cs[1024];
    __shared__ u32 h2[4096];
    __shared__ u32 h3[16];
    __shared__ u32 sB, sAcc, sB2, sAcc2, sFound;
    int t = threadIdx.x;
    const int wave = t >> 6, lane = t & 63;
    if (t == 0) sFound = 0;
    if (t == 1) { cnt[1] = 0; cnt[2] = 0; }
    u32 s1 = 0;
    if (t < H1_BINS) {
        for (int j = 0; j < HIST1_GRID; j++) s1 += hist1p[j * H1_BINS + t];
    }
    cs[t] = (t < H1_BINS) ? s1 : 0u;
    for (int i = t; i < 4096; i += 1024) h2[i] = 0;
    if (t < 16) h3[t] = 0;
    __syncthreads();
    for (int d = 1; d < 1024; d <<= 1) {          // inclusive suffix sum
        u32 v = (t + d < 1024) ? cs[t + d] : 0u;
        __syncthreads();
        cs[t] += v;
        __syncthreads();
    }
    {
        u32 S_t = cs[t];
        u32 S_next = (t < 1023) ? cs[t + 1] : 0u;
        if (S_next < TOPK && S_t >= TOPK) { sB = (u32)t; sAcc = S_next; sFound = 1; }
    }
    __syncthreads();
    if (!sFound) {
        if (t == 0) { cnt[5] = 0u; cnt[6] = 0u; }
        return;
    }
    const u32 Bhi = sB + H1_BASE;
    // level-2: coalesced per-wave region scan, hist bits[15:4]
    for (u32 reg = wave; reg < CAND_GRID; reg += 16) {
        u32 n = candCnt[reg]; if (n > REG_CAP) n = REG_CAP;
        const u32* kp = candKey + reg * REG_CAP;
        for (u32 i = lane; i < n; i += 64) {
            u32 k = kp[i];
            if ((k >> 16) == Bhi) atomicAdd(&h2[(k >> 4) & 0xFFFu], 1u);
        }
    }
    __syncthreads();
    {
        u32 c4 = h2[4 * t] + h2[4 * t + 1] + h2[4 * t + 2] + h2[4 * t + 3];
        __syncthreads();
        cs[t] = c4;
    }
    __syncthreads();
    for (int d = 1; d < 1024; d <<= 1) {
        u32 v = (t + d < 1024) ? cs[t + d] : 0u;
        __syncthreads();
        cs[t] += v;
        __syncthreads();
    }
    {
        u32 C = sAcc;
        u32 S_t = C + cs[t];
        u32 S_next = C + ((t < 1023) ? cs[t + 1] : 0u);
        if (S_next < TOPK && S_t >= TOPK) {
            u32 acc = S_next;
            int b2 = 4 * t;
            for (int b = 4 * t + 3; b >= 4 * t; b--) {
                u32 h = h2[b];
                if (acc + h >= TOPK) { b2 = b; break; }
                acc += h;
            }
            sB2 = (u32)b2; sAcc2 = acc;
        }
    }
    __syncthreads();
    const u32 pre24 = (Bhi << 12) | sB2;          // bits [31:4] of cut
    // level-3: rescan, hist bits[3:0]
    for (u32 reg = wave; reg < CAND_GRID; reg += 16) {
        u32 n = candCnt[reg]; if (n > REG_CAP) n = REG_CAP;
        const u32* kp = candKey + reg * REG_CAP;
        for (u32 i = lane; i < n; i += 64) {
            u32 k = kp[i];
            if ((k >> 4) == pre24) atomicAdd(&h3[k & 0xFu], 1u);
        }
    }
    __syncthreads();
    if (t == 0) {
        u32 acc = sAcc2;
        int L = 0;
        for (int b = 15; b >= 0; b--) {
            u32 h = h3[b];
            if (acc + h >= TOPK) { L = b; break; }
            acc += h;
        }
        cnt[5] = (pre24 << 4) | (u32)L;           // exact cutoff key
        cnt[6] = TOPK - acc;                      // take from ==cutoff set
    }
}

// block-aggregated collect over 2 regions/block
__global__ void __launch_bounds__(256) k_collect(const u32* __restrict__ candKey,
                                                 const u32* __restrict__ candIdx,
                                                 const u32* __restrict__ candCnt,
                                                 u32* __restrict__ cnt,
                                                 u64* __restrict__ sel,
                                                 u32* __restrict__ eqI) {
    __shared__ u64 sStage[COLL_CAP];
    __shared__ u32 eStage[COLL_CAP];
    __shared__ u32 sc, ec, sb, eb;
    int t = threadIdx.x;
    if (t == 0) { sc = 0; ec = 0; }
    __syncthreads();
    u32 cut = cnt[5];
    for (int rr = 0; rr < 2; rr++) {
        u32 reg = blockIdx.x * 2 + rr;
        u32 n = candCnt[reg]; if (n > REG_CAP) n = REG_CAP;
        u32 base = reg * REG_CAP;
        for (u32 i = t; i < n; i += 256) {
            u32 k = candKey[base + i];
            if (k > cut) {
                u32 p = atomicAdd(&sc, 1u);
                sStage[p] = ((u64)k << 32) | (u64)(0xFFFFFFFFu - candIdx[base + i]);
            } else if (k == cut) {
                u32 e2 = atomicAdd(&ec, 1u);
                eStage[e2] = candIdx[base + i];
            }
        }
    }
    __syncthreads();
    if (t == 0) {
        sb = sc ? atomicAdd(&cnt[1], sc) : 0u;
        eb = ec ? atomicAdd(&cnt[2], ec) : 0u;
    }
    __syncthreads();
    for (u32 i = t; i < sc; i += 256) { u32 g = sb + i; if (g < TOPK) sel[g] = sStage[i]; }
    for (u32 i = t; i < ec; i += 256) { u32 g = eb + i; if (g < EQCAP) eqI[g] = eStage[i]; }
}

// counting-rank: hi16-bin histogram + suffix-sum + bin-grouped scatter +
// within-bin linear rank (low 48 bits = value-desc, idx-asc). Exact permutation.
__global__ void __launch_bounds__(1024) k_rank(const u64* __restrict__ sel,
                                               const u32* __restrict__ eqI,
                                               const u32* __restrict__ cnt,
                                               const float* __restrict__ boxes,
                                               float* __restrict__ rboxes, float* __restrict__ rvals,
                                               int* __restrict__ rlabel, float* __restrict__ out) {
    __shared__ u64 binned[TOPK];      // 32 KB
    __shared__ u32 hist[H1_BINS];
    __shared__ u32 base[H1_BINS];
    __shared__ u32 cur[H1_BINS];
    __shared__ u32 cs[1024];
    int t = threadIdx.x;
    u32 nsel = cnt[1] < (u32)TOPK ? cnt[1] : (u32)TOPK;
    u32 m = cnt[2] < (u32)EQCAP ? cnt[2] : (u32)EQCAP;
    u32 need = cnt[6];
    if (nsel + need > (u32)TOPK) need = TOPK - nsel;
    u32 cut = cnt[5];
    u32 covered = nsel + need;
    // degenerate-underfill guard: zero only the uncovered tail (normally empty)
    for (u32 r = covered + t; r < TOPK; r += 1024) {
        rboxes[r * 4 + 0] = 0; rboxes[r * 4 + 1] = 0;
        rboxes[r * 4 + 2] = 0; rboxes[r * 4 + 3] = 0;
        rvals[r] = 0.0f; rlabel[r] = 0;
        out[TOPK * 5 + r] = 0.0f;
        out[TOPK * 6 + r] = 0.0f;
        float* d = out + (size_t)r * 5;
        d[0] = 0; d[1] = 0; d[2] = 0; d[3] = 0; d[4] = 0;
    }
    for (int i = t; i < H1_BINS; i += 1024) { hist[i] = 0; cur[i] = 0; }
    __syncthreads();
    for (u32 i = t; i < nsel; i += 1024) {
        u32 b = (u32)(sel[i] >> 48) - H1_BASE;
        atomicAdd(&hist[b], 1u);
    }
    __syncthreads();
    cs[t] = (t < H1_BINS) ? hist[t] : 0u;
    __syncthreads();
    for (int d = 1; d < 1024; d <<= 1) {          // inclusive suffix sum
        u32 v = (t + d < 1024) ? cs[t + d] : 0u;
        __syncthreads();
        cs[t] += v;
        __syncthreads();
    }
    if (t < H1_BINS) base[t] = (t + 1 < 1024) ? cs[t + 1] : 0u;  // # in bins > t
    __syncthreads();
    for (u32 i = t; i < nsel; i += 1024) {
        u64 c = sel[i];
        u32 b = (u32)(c >> 48) - H1_BASE;
        u32 p = base[b] + atomicAdd(&cur[b], 1u);
        binned[p] = c;
    }
    __syncthreads();

    for (u32 p = t; p < nsel; p += 1024) {
        u64 c = binned[p];
        u32 b = (u32)(c >> 48) - H1_BASE;
        u32 s0 = base[b], cb = hist[b];
        u32 r = s0;
        for (u32 qq = s0; qq < s0 + cb; qq++) r += (binned[qq] > c) ? 1u : 0u;
        u32 idx = 0xFFFFFFFFu - (u32)(c & 0xFFFFFFFFull);
        float val = __uint_as_float((u32)(c >> 32));
        u32 bi = idx / NCLS;
        u32 lab = idx % NCLS;
        const float* bp = boxes + (size_t)bi * 4;
        float x1 = fminf(fmaxf(bp[0], 0.0f), IMGW_M1);
        float y1 = fminf(fmaxf(bp[1], 0.0f), IMGH_M1);
        float x2 = fminf(fmaxf(bp[2], 0.0f), IMGW_M1);
        float y2 = fminf(fmaxf(bp[3], 0.0f), IMGH_M1);
        rboxes[r * 4 + 0] = x1; rboxes[r * 4 + 1] = y1;
        rboxes[r * 4 + 2] = x2; rboxes[r * 4 + 3] = y2;
        rvals[r] = val;
        rlabel[r] = (int)lab;
        out[TOPK * 5 + r] = (float)lab;
    }
    // eq entries (key == cut): rank by ascending idx, take `need`
    for (u32 j = t; j < m; j += 1024) {
        u32 v = eqI[j];
        u32 rho = 0;
        for (u32 k = 0; k < m; k++) rho += (eqI[k] < v) ? 1u : 0u;  // unique
        if (rho < need) {
            u32 r = nsel + rho;
            float val = __uint_as_float(cut);
            u32 bi = v / NCLS;
            u32 lab = v % NCLS;
            const float* bp = boxes + (size_t)bi * 4;
            float x1 = fminf(fmaxf(bp[0], 0.0f), IMGW_M1);
            float y1 = fminf(fmaxf(bp[1], 0.0f), IMGH_M1);
            float x2 = fminf(fmaxf(bp[2], 0.0f), IMGW_M1);
            float y2 = fminf(fmaxf(bp[3], 0.0f), IMGH_M1);
            rboxes[r * 4 + 0] = x1; rboxes[r * 4 + 1] = y1;
            rboxes[r * 4 + 2] = x2; rboxes[r * 4 + 3] = y2;
            rvals[r] = val;
            rlabel[r] = (int)lab;
            out[TOPK * 5 + r] = (float)lab;
        }
    }
}

// per-class greedy NMS, ONE WAVE per class: ballot-compacted stable membership,
// single-wave barriers (cheap). Class-local suppression is exact (label*4096
// offset separates classes by >= 2763 px; clipped boxes <= 1333 wide).
__global__ void __launch_bounds__(64) k_nms(const float* __restrict__ rboxes,
                                            const float* __restrict__ rvals,
                                            const int* __restrict__ rlabel,
                                            float* __restrict__ out) {
    int c = blockIdx.x + 1;                     // labels 1..80
    __shared__ unsigned short mem[TOPK];
    __shared__ unsigned char keepL[TOPK];
    int lane = threadIdx.x;
    u64 laneLT = ((u64)1 << lane) - 1;
    u32 mcount = 0;
    for (int b0 = 0; b0 < TOPK; b0 += 64) {     // stable, coalesced compaction
        int r = b0 + lane;
        bool match = (rlabel[r] == c);
        u64 mask = __ballot(match);
        if (match) mem[mcount + (u32)__popcll(mask & laneLT)] = (unsigned short)r;
        mcount += (u32)__popcll(mask);
    }
    u32 m = mcount;                              // wave-uniform
    for (u32 q = lane; q < m; q += 64) keepL[q] = 1;
    __syncthreads();

    float off = (float)c * 4096.0f;              // replicate reference's f32 rounding
    for (u32 i = 0; i < m; i++) {
        __syncthreads();
        if (!keepL[i]) continue;                 // uniform branch
        int ri = mem[i];
        float ix1 = rboxes[ri * 4 + 0] + off, iy1 = rboxes[ri * 4 + 1] + off;
        float ix2 = rboxes[ri * 4 + 2] + off, iy2 = rboxes[ri * 4 + 3] + off;
        float iarea = (ix2 - ix1) * (iy2 - iy1);
        for (u32 jj = i + 1 + lane; jj < m; jj += 64) {
            if (!keepL[jj]) continue;
            int rj = mem[jj];
            float jx1 = rboxes[rj * 4 + 0] + off, jy1 = rboxes[rj * 4 + 1] + off;
            float jx2 = rboxes[rj * 4 + 2] + off, jy2 = rboxes[rj * 4 + 3] + off;
            float iw = fmaxf(fminf(ix2, jx2) - fmaxf(ix1, jx1), 0.0f);
            float ih = fmaxf(fminf(iy2, jy2) - fmaxf(iy1, jy1), 0.0f);
            float inter = iw * ih;
            float jarea = (jx2 - jx1) * (jy2 - jy1);
            float iou = inter / (iarea + jarea - inter + 1e-9f);
            if (iou > 0.5f) keepL[jj] = 0;
        }
    }
    __syncthreads();
    for (u32 q = lane; q < m; q += 64) {
        int r = mem[q];
        int k = keepL[q];
        out[TOPK * 6 + r] = k ? 1.0f : 0.0f;
        float* d = out + (size_t)r * 5;
        if (k) {
            d[0] = rboxes[r * 4 + 0]; d[1] = rboxes[r * 4 + 1];
            d[2] = rboxes[r * 4 + 2]; d[3] = rboxes[r * 4 + 3];
            d[4] = rvals[r];
        } else {
            d[0] = 0; d[1] = 0; d[2] = 0; d[3] = 0; d[4] = 0;
        }
    }
}

extern "C" void kernel_launch(void* const* d_in, const int* in_sizes, int n_in,
                              void* d_out, int out_size, void* d_ws, size_t ws_size,
                              hipStream_t stream) {
    const float* x = (const float*)d_in[0];
    const float* boxes = (const float*)d_in[1];
    float* out = (float*)d_out;

    u32* W = (u32*)d_ws;
    u32* cnt = W;                                          // 16
    u32* hist1p = W + 16;                                  // 64*576 = 36864
    u32* candCnt = W + 16 + 36864;                         // 1024
    u32* candKey = candCnt + 1024;                         // 655360
    u32* candIdx = candKey + CAND_GRID * REG_CAP;          // 655360
    u64* sel = (u64*)(candIdx + CAND_GRID * REG_CAP);      // 4096 u64 (8B aligned)
    u32* eqI = (u32*)(sel + TOPK);                         // 8192
    float* rboxes = (float*)(eqI + EQCAP);                 // 16384
    float* rvals = rboxes + 4 * TOPK;                      // 4096
    int* rlabel = (int*)(rvals + TOPK);                    // 4096

    k_cand<<<CAND_GRID, CAND_THREADS, 0, stream>>>(x, candKey, candIdx, candCnt);
    k_hist1<<<HIST1_GRID, 256, 0, stream>>>(candKey, candCnt, hist1p);
    k_mid2<<<1, 1024, 0, stream>>>(candKey, candCnt, hist1p, cnt);
    k_collect<<<COLL_GRID, 256, 0, stream>>>(candKey, candIdx, candCnt, cnt, sel, eqI);
    k_rank<<<1, 1024, 0, stream>>>(sel, eqI, cnt, boxes, rboxes, rvals, rlabel, out);
    k_nms<<<80, 64, 0, stream>>>(rboxes, rvals, rlabel, out);
}

// Round 9
// 190.654 us; speedup vs baseline: 1.2468x; 1.2468x over previous
//
#include <hip/hip_runtime.h>

#pragma clang fp contract(off)

typedef unsigned int u32;
typedef unsigned long long u64;
typedef long long i64;

#define N_ROWS 32768
#define NCLS 81
#define TOPK 4096
#define MAXCAND 327680
#define EQCAP 8192
#define IMGW_M1 1332.0f
#define IMGH_M1 799.0f

// k_cand geometry: 8 threads/row, 32 rows/block, 1024 blocks
#define CAND_THREADS 256
#define RPB 32
#define CAND_GRID (N_ROWS / RPB)          // 1024
#define CPT 11
#define BLK_CAND_CAP 640                  // 32 rows * <=19 cand/row = 608 max
#define ROW_F4 ((RPB * NCLS) / 4)         // 648 float4 per block slice (exactly)

// level-1 bins: f32 bits of p in (0.05, 1.0] -> hi16 in [0x3D4C, 0x3F80]
#define H1_BASE 0x3D4Cu
#define H1_BINS 576
#define HIST1_GRID 64

#define COLL_GRID 512
#define COLL_CAP 640                      // >= ceil(MAXCAND / COLL_GRID)

// ---------------- ws layout (u32 units) ----------------
// cnt[16]: 0=candCount 1=selCount 2=eqCount 5=cutKey 6=numFromEqual
//          (0 zeroed by k_cand block0-independent? no: see k_cand atomic — cnt[0]
//           must start 0: k_mid zeroes 1,2; cnt[0] zeroed by a 1-thread prelude in k_cand? 
//           -> handled: k_cand uses atomicAdd on cnt[0]; we zero it in k_nms? No.
//           We zero cnt[0] via hipMemsetAsync in kernel_launch (graph-safe).)
// hist1p[64*576]  atomic-free partial level-1 hists
// candKey[MAXCAND], candIdx[MAXCAND]  (dense)
// sel u64[4096], eqI[8192], rboxes[4096*4], rvals[4096], rlabel[4096]

// fast f64 exp for d <= 0 (clamped at -45). Cody-Waite + Taylor-13.
// Relative error ~3e-16 — decisions have >= f32-ulp (6e-8) margins.
__device__ inline double fast_exp_neg(double d) {
    if (d < -45.0) return 0.0;
    const double L2E    = 1.4426950408889634074;
    const double LN2_HI = 6.93147180369123816490e-01;
    const double LN2_LO = 1.90821492927058770002e-10;
    double n = __builtin_rint(d * L2E);
    double r = __builtin_fma(-n, LN2_HI, d);
    r = __builtin_fma(-n, LN2_LO, r);
    double p = 1.0 / 6227020800.0;
    p = __builtin_fma(p, r, 1.0 / 479001600.0);
    p = __builtin_fma(p, r, 1.0 / 39916800.0);
    p = __builtin_fma(p, r, 1.0 / 3628800.0);
    p = __builtin_fma(p, r, 1.0 / 362880.0);
    p = __builtin_fma(p, r, 1.0 / 40320.0);
    p = __builtin_fma(p, r, 1.0 / 5040.0);
    p = __builtin_fma(p, r, 1.0 / 720.0);
    p = __builtin_fma(p, r, 1.0 / 120.0);
    p = __builtin_fma(p, r, 1.0 / 24.0);
    p = __builtin_fma(p, r, 1.0 / 6.0);
    p = __builtin_fma(p, r, 0.5);
    p = __builtin_fma(p, r, 1.0);
    p = __builtin_fma(p, r, 1.0);
    i64 ni = (i64)n;
    double sc = __longlong_as_double((i64)(1023 + ni) << 52);
    return p * sc;
}

// softmax + threshold + DENSE compaction (block-local staging, one global
// atomic per block). Arithmetic identical to passing R7 -> bit-identical.
__global__ void __launch_bounds__(256) k_cand(const float* __restrict__ x,
                                              u32* __restrict__ candKey,
                                              u32* __restrict__ candIdx,
                                              u32* __restrict__ cnt) {
    __shared__ float4 lx4[ROW_F4];
    __shared__ u32 lK[BLK_CAND_CAP];
    __shared__ u32 lI[BLK_CAND_CAP];
    __shared__ u32 lcnt;
    __shared__ u32 gbaseSh;
    float* lx = (float*)lx4;
    const int t = threadIdx.x;
    if (t == 0) lcnt = 0;

    const float4* xv = (const float4*)x + (size_t)blockIdx.x * ROW_F4;
    for (int i = t; i < ROW_F4; i += CAND_THREADS) lx4[i] = xv[i];
    __syncthreads();

    const int rl = t >> 3;
    const int q = t & 7;
    const int c0 = q * 10;
    const int cEff = (q == 7) ? 11 : 10;
    const int row = blockIdx.x * RPB + rl;
    const float* xr = lx + rl * NCLS;

    float v[CPT];
    #pragma unroll
    for (int i = 0; i < CPT; i++) v[i] = (i < cEff) ? xr[c0 + i] : -1.0e30f;

    float m = v[0];
    #pragma unroll
    for (int i = 1; i < CPT; i++) m = fmaxf(m, v[i]);
    m = fmaxf(m, __shfl_xor(m, 1));
    m = fmaxf(m, __shfl_xor(m, 2));
    m = fmaxf(m, __shfl_xor(m, 4));

    double s = 0.0;
    #pragma unroll
    for (int i = 0; i < CPT; i++) {
        if (i < cEff) {
            float d = v[i] - m;
            s += fast_exp_neg((double)d);
        }
    }
    s += __shfl_xor(s, 1);
    s += __shfl_xor(s, 2);
    s += __shfl_xor(s, 4);

    const double THRMID = (double)0.05f + 0x1.0p-29;
    double ethr = THRMID * s;
    #pragma unroll
    for (int i = 0; i < CPT; i++) {
        int c = c0 + i;
        if (i < cEff && c != 0) {
            float d = v[i] - m;
            double e = fast_exp_neg((double)d);
            if (e > ethr) {
                float pf = (float)(e / s);
                u32 slot = atomicAdd(&lcnt, 1u);
                lK[slot] = __float_as_uint(pf);
                lI[slot] = (u32)(row * NCLS + c);
            }
        }
    }
    __syncthreads();
    u32 tot = lcnt;
    if (t == 0) gbaseSh = tot ? atomicAdd(&cnt[0], tot) : 0u;
    __syncthreads();
    u32 gbase = gbaseSh;
    for (u32 i = t; i < tot; i += CAND_THREADS) {
        u32 g = gbase + i;
        if (g < MAXCAND) {
            candKey[g] = lK[i];
            candIdx[g] = lI[i];
        }
    }
}

// DENSE grid-stride level-1 histogram -> atomic-free partial slices
__global__ void __launch_bounds__(256) k_hist1(const u32* __restrict__ candKey,
                                               const u32* __restrict__ cnt,
                                               u32* __restrict__ hist1p) {
    __shared__ u32 lh[H1_BINS];
    int t = threadIdx.x;
    for (int i = t; i < H1_BINS; i += 256) lh[i] = 0;
    __syncthreads();
    u32 n = cnt[0] < (u32)MAXCAND ? cnt[0] : (u32)MAXCAND;
    u32 stride = HIST1_GRID * 256;
    for (u32 i = blockIdx.x * 256 + t; i < n; i += stride) {
        u32 b = (candKey[i] >> 16) - H1_BASE;
        if (b < (u32)H1_BINS) atomicAdd(&lh[b], 1u);
    }
    __syncthreads();
    u32 ob = blockIdx.x * H1_BINS;
    for (int i = t; i < H1_BINS; i += 256) hist1p[ob + i] = lh[i];
}

// fused cutoff finder, all-LDS, DENSE pipelined scans:
// level-1 (sum partials + suffix scan) -> scan A: bits[15:4] 4096-bin LDS hist
// -> scan B: bits[3:0] 16-bin. Also zeroes cnt[1]/cnt[2] for k_collect.
__global__ void __launch_bounds__(1024) k_mid(const u32* __restrict__ candKey,
                                              const u32* __restrict__ hist1p,
                                              u32* __restrict__ cnt) {
    __shared__ u32 cs[1024];
    __shared__ u32 h2[4096];
    __shared__ u32 h3[16];
    __shared__ u32 sB, sAcc, sB2, sAcc2, sFound;
    int t = threadIdx.x;
    if (t == 0) sFound = 0;
    if (t == 1) { cnt[1] = 0; cnt[2] = 0; }
    u32 s1 = 0;
    if (t < H1_BINS) {
        for (int j = 0; j < HIST1_GRID; j++) s1 += hist1p[j * H1_BINS + t];  // coalesced
    }
    cs[t] = (t < H1_BINS) ? s1 : 0u;
    for (int i = t; i < 4096; i += 1024) h2[i] = 0;
    if (t < 16) h3[t] = 0;
    __syncthreads();
    for (int d = 1; d < 1024; d <<= 1) {          // inclusive suffix sum
        u32 v = (t + d < 1024) ? cs[t + d] : 0u;
        __syncthreads();
        cs[t] += v;
        __syncthreads();
    }
    {
        u32 S_t = cs[t];
        u32 S_next = (t < 1023) ? cs[t + 1] : 0u;
        if (S_next < TOPK && S_t >= TOPK) { sB = (u32)t; sAcc = S_next; sFound = 1; }
    }
    __syncthreads();
    if (!sFound) {
        if (t == 0) { cnt[5] = 0u; cnt[6] = 0u; }
        return;
    }
    const u32 Bhi = sB + H1_BASE;
    const u32 n = cnt[0] < (u32)MAXCAND ? cnt[0] : (u32)MAXCAND;
    // scan A: dense, coalesced, pipelined
    for (u32 i = t; i < n; i += 1024) {
        u32 k = candKey[i];
        if ((k >> 16) == Bhi) atomicAdd(&h2[(k >> 4) & 0xFFFu], 1u);
    }
    __syncthreads();
    u32 c4 = h2[4 * t] + h2[4 * t + 1] + h2[4 * t + 2] + h2[4 * t + 3];
    __syncthreads();
    cs[t] = c4;
    __syncthreads();
    for (int d = 1; d < 1024; d <<= 1) {
        u32 v = (t + d < 1024) ? cs[t + d] : 0u;
        __syncthreads();
        cs[t] += v;
        __syncthreads();
    }
    {
        u32 C = sAcc;
        u32 S_t = C + cs[t];
        u32 S_next = C + ((t < 1023) ? cs[t + 1] : 0u);
        if (S_next < TOPK && S_t >= TOPK) {
            u32 acc = S_next;
            int b2 = 4 * t;
            for (int b = 4 * t + 3; b >= 4 * t; b--) {
                u32 h = h2[b];
                if (acc + h >= TOPK) { b2 = b; break; }
                acc += h;
            }
            sB2 = (u32)b2; sAcc2 = acc;
        }
    }
    __syncthreads();
    const u32 pre28 = (Bhi << 12) | sB2;          // bits [31:4] of cut
    // scan B: dense
    for (u32 i = t; i < n; i += 1024) {
        u32 k = candKey[i];
        if ((k >> 4) == pre28) atomicAdd(&h3[k & 0xFu], 1u);
    }
    __syncthreads();
    if (t == 0) {
        u32 acc = sAcc2;
        int L = 0;
        for (int b = 15; b >= 0; b--) {
            u32 h = h3[b];
            if (acc + h >= TOPK) { L = b; break; }
            acc += h;
        }
        cnt[5] = (pre28 << 4) | (u32)L;           // exact cutoff key
        cnt[6] = TOPK - acc;                      // take from ==cutoff set
    }
}

// block-aggregated collect over dense chunks
__global__ void __launch_bounds__(256) k_collect(const u32* __restrict__ candKey,
                                                 const u32* __restrict__ candIdx,
                                                 u32* __restrict__ cnt,
                                                 u64* __restrict__ sel,
                                                 u32* __restrict__ eqI) {
    __shared__ u64 sStage[COLL_CAP];
    __shared__ u32 eStage[COLL_CAP];
    __shared__ u32 sc, ec, sb, eb;
    int t = threadIdx.x;
    if (t == 0) { sc = 0; ec = 0; }
    __syncthreads();
    u32 n = cnt[0] < (u32)MAXCAND ? cnt[0] : (u32)MAXCAND;
    u32 chunk = (n + COLL_GRID - 1) / COLL_GRID;  // <= 640 by construction
    u32 lo = blockIdx.x * chunk;
    u32 hi = lo + chunk; if (hi > n) hi = n;
    u32 cut = cnt[5];
    for (u32 i = lo + t; i < hi; i += 256) {
        u32 k = candKey[i];
        if (k > cut) {
            u32 p = atomicAdd(&sc, 1u);
            sStage[p] = ((u64)k << 32) | (u64)(0xFFFFFFFFu - candIdx[i]);
        } else if (k == cut) {
            u32 e2 = atomicAdd(&ec, 1u);
            eStage[e2] = candIdx[i];
        }
    }
    __syncthreads();
    if (t == 0) {
        sb = sc ? atomicAdd(&cnt[1], sc) : 0u;
        eb = ec ? atomicAdd(&cnt[2], ec) : 0u;
    }
    __syncthreads();
    for (u32 i = t; i < sc; i += 256) { u32 g = sb + i; if (g < TOPK) sel[g] = sStage[i]; }
    for (u32 i = t; i < ec; i += 256) { u32 g = eb + i; if (g < EQCAP) eqI[g] = eStage[i]; }
}

// counting-rank: hi16-bin histogram + suffix-sum + bin-grouped scatter +
// within-bin linear rank (low 48 bits = value-desc, idx-asc). Exact permutation.
// Tail-only zero (covered == TOPK in all non-degenerate cases).
__global__ void __launch_bounds__(1024) k_rank(const u64* __restrict__ sel,
                                               const u32* __restrict__ eqI,
                                               const u32* __restrict__ cnt,
                                               const float* __restrict__ boxes,
                                               float* __restrict__ rboxes, float* __restrict__ rvals,
                                               int* __restrict__ rlabel, float* __restrict__ out) {
    __shared__ u64 binned[TOPK];      // 32 KB
    __shared__ u32 hist[H1_BINS];
    __shared__ u32 base[H1_BINS];
    __shared__ u32 cur[H1_BINS];
    __shared__ u32 cs[1024];
    int t = threadIdx.x;
    u32 nsel = cnt[1] < (u32)TOPK ? cnt[1] : (u32)TOPK;
    u32 m = cnt[2] < (u32)EQCAP ? cnt[2] : (u32)EQCAP;
    u32 need = cnt[6];
    if (nsel + need > (u32)TOPK) need = TOPK - nsel;
    u32 cut = cnt[5];
    u32 covered = nsel + need;
    for (u32 r = covered + t; r < TOPK; r += 1024) {   // degenerate-only tail
        rboxes[r * 4 + 0] = 0; rboxes[r * 4 + 1] = 0;
        rboxes[r * 4 + 2] = 0; rboxes[r * 4 + 3] = 0;
        rvals[r] = 0.0f; rlabel[r] = 0;
        out[TOPK * 5 + r] = 0.0f;
        out[TOPK * 6 + r] = 0.0f;
        float* d = out + (size_t)r * 5;
        d[0] = 0; d[1] = 0; d[2] = 0; d[3] = 0; d[4] = 0;
    }
    for (int i = t; i < H1_BINS; i += 1024) { hist[i] = 0; cur[i] = 0; }
    __syncthreads();
    for (u32 i = t; i < nsel; i += 1024) {
        u32 b = (u32)(sel[i] >> 48) - H1_BASE;
        if (b >= (u32)H1_BINS) b = 0;              // degenerate-only clamp
        atomicAdd(&hist[b], 1u);
    }
    __syncthreads();
    cs[t] = (t < H1_BINS) ? hist[t] : 0u;
    __syncthreads();
    for (int d = 1; d < 1024; d <<= 1) {          // inclusive suffix sum
        u32 v = (t + d < 1024) ? cs[t + d] : 0u;
        __syncthreads();
        cs[t] += v;
        __syncthreads();
    }
    if (t < H1_BINS) base[t] = (t + 1 < 1024) ? cs[t + 1] : 0u;  // # in bins > t
    __syncthreads();
    for (u32 i = t; i < nsel; i += 1024) {
        u64 c = sel[i];
        u32 b = (u32)(c >> 48) - H1_BASE;
        if (b >= (u32)H1_BINS) b = 0;
        u32 p = base[b] + atomicAdd(&cur[b], 1u);
        if (p < (u32)TOPK) binned[p] = c;
    }
    __syncthreads();

    for (u32 p = t; p < nsel; p += 1024) {
        u64 c = binned[p];
        u32 b = (u32)(c >> 48) - H1_BASE;
        if (b >= (u32)H1_BINS) b = 0;
        u32 s0 = base[b], cb = hist[b];
        u32 r = s0;
        for (u32 qq = s0; qq < s0 + cb; qq++) r += (binned[qq] > c) ? 1u : 0u;
        u32 idx = 0xFFFFFFFFu - (u32)(c & 0xFFFFFFFFull);
        float val = __uint_as_float((u32)(c >> 32));
        u32 bi = idx / NCLS;
        u32 lab = idx % NCLS;
        const float* bp = boxes + (size_t)bi * 4;
        float x1 = fminf(fmaxf(bp[0], 0.0f), IMGW_M1);
        float y1 = fminf(fmaxf(bp[1], 0.0f), IMGH_M1);
        float x2 = fminf(fmaxf(bp[2], 0.0f), IMGW_M1);
        float y2 = fminf(fmaxf(bp[3], 0.0f), IMGH_M1);
        rboxes[r * 4 + 0] = x1; rboxes[r * 4 + 1] = y1;
        rboxes[r * 4 + 2] = x2; rboxes[r * 4 + 3] = y2;
        rvals[r] = val;
        rlabel[r] = (int)lab;
        out[TOPK * 5 + r] = (float)lab;
    }
    // eq entries (key == cut): rank by ascending idx, take `need`
    for (u32 j = t; j < m; j += 1024) {
        u32 v = eqI[j];
        u32 rho = 0;
        for (u32 k = 0; k < m; k++) rho += (eqI[k] < v) ? 1u : 0u;  // unique
        if (rho < need) {
            u32 r = nsel + rho;
            float val = __uint_as_float(cut);
            u32 bi = v / NCLS;
            u32 lab = v % NCLS;
            const float* bp = boxes + (size_t)bi * 4;
            float x1 = fminf(fmaxf(bp[0], 0.0f), IMGW_M1);
            float y1 = fminf(fmaxf(bp[1], 0.0f), IMGH_M1);
            float x2 = fminf(fmaxf(bp[2], 0.0f), IMGW_M1);
            float y2 = fminf(fmaxf(bp[3], 0.0f), IMGH_M1);
            rboxes[r * 4 + 0] = x1; rboxes[r * 4 + 1] = y1;
            rboxes[r * 4 + 2] = x2; rboxes[r * 4 + 3] = y2;
            rvals[r] = val;
            rlabel[r] = (int)lab;
            out[TOPK * 5 + r] = (float)lab;
        }
    }
}

// per-class greedy NMS, one wave per class (ballot-compacted stable membership).
// Class-local suppression is exact (label*4096 offset separates classes by
// >= 2763 px; clipped boxes <= 1333 wide).
__global__ void __launch_bounds__(64) k_nms(const float* __restrict__ rboxes,
                                            const float* __restrict__ rvals,
                                            const int* __restrict__ rlabel,
                                            float* __restrict__ out) {
    int c = blockIdx.x + 1;                     // labels 1..80
    __shared__ unsigned short mem[TOPK];
    __shared__ unsigned char keepL[TOPK];
    int lane = threadIdx.x;
    u64 laneLT = ((u64)1 << lane) - 1;
    u32 mcount = 0;
    for (int b0 = 0; b0 < TOPK; b0 += 64) {     // stable, coalesced compaction
        int r = b0 + lane;
        bool match = (rlabel[r] == c);
        u64 mask = __ballot(match);
        if (match) mem[mcount + (u32)__popcll(mask & laneLT)] = (unsigned short)r;
        mcount += (u32)__popcll(mask);
    }
    u32 m = mcount;                              // wave-uniform
    for (u32 q = lane; q < m; q += 64) keepL[q] = 1;
    __syncthreads();

    float off = (float)c * 4096.0f;              // replicate reference's f32 rounding
    for (u32 i = 0; i < m; i++) {
        __syncthreads();
        if (!keepL[i]) continue;                 // uniform branch
        int ri = mem[i];
        float ix1 = rboxes[ri * 4 + 0] + off, iy1 = rboxes[ri * 4 + 1] + off;
        float ix2 = rboxes[ri * 4 + 2] + off, iy2 = rboxes[ri * 4 + 3] + off;
        float iarea = (ix2 - ix1) * (iy2 - iy1);
        for (u32 jj = i + 1 + lane; jj < m; jj += 64) {
            if (!keepL[jj]) continue;
            int rj = mem[jj];
            float jx1 = rboxes[rj * 4 + 0] + off, jy1 = rboxes[rj * 4 + 1] + off;
            float jx2 = rboxes[rj * 4 + 2] + off, jy2 = rboxes[rj * 4 + 3] + off;
            float iw = fmaxf(fminf(ix2, jx2) - fmaxf(ix1, jx1), 0.0f);
            float ih = fmaxf(fminf(iy2, jy2) - fmaxf(iy1, jy1), 0.0f);
            float inter = iw * ih;
            float jarea = (jx2 - jx1) * (jy2 - jy1);
            float iou = inter / (iarea + jarea - inter + 1e-9f);
            if (iou > 0.5f) keepL[jj] = 0;
        }
    }
    __syncthreads();
    for (u32 q = lane; q < m; q += 64) {
        int r = mem[q];
        int k = keepL[q];
        out[TOPK * 6 + r] = k ? 1.0f : 0.0f;
        float* d = out + (size_t)r * 5;
        if (k) {
            d[0] = rboxes[r * 4 + 0]; d[1] = rboxes[r * 4 + 1];
            d[2] = rboxes[r * 4 + 2]; d[3] = rboxes[r * 4 + 3];
            d[4] = rvals[r];
        } else {
            d[0] = 0; d[1] = 0; d[2] = 0; d[3] = 0; d[4] = 0;
        }
    }
}

extern "C" void kernel_launch(void* const* d_in, const int* in_sizes, int n_in,
                              void* d_out, int out_size, void* d_ws, size_t ws_size,
                              hipStream_t stream) {
    const float* x = (const float*)d_in[0];
    const float* boxes = (const float*)d_in[1];
    float* out = (float*)d_out;

    u32* W = (u32*)d_ws;
    u32* cnt = W;                                          // 16
    u32* hist1p = W + 16;                                  // 64*576 = 36864
    u32* candKey = W + 16 + 36864;                         // MAXCAND
    u32* candIdx = candKey + MAXCAND;                      // MAXCAND
    u64* sel = (u64*)(candIdx + MAXCAND);                  // 4096 u64 (8B aligned)
    u32* eqI = (u32*)(sel + TOPK);                         // 8192
    float* rboxes = (float*)(eqI + EQCAP);                 // 16384
    float* rvals = rboxes + 4 * TOPK;                      // 4096
    int* rlabel = (int*)(rvals + TOPK);                    // 4096

    hipMemsetAsync(cnt, 0, 16 * sizeof(u32), stream);      // graph-capture-safe async memset
    k_cand<<<CAND_GRID, CAND_THREADS, 0, stream>>>(x, candKey, candIdx, cnt);
    k_hist1<<<HIST1_GRID, 256, 0, stream>>>(candKey, cnt, hist1p);
    k_mid<<<1, 1024, 0, stream>>>(candKey, hist1p, cnt);
    k_collect<<<COLL_GRID, 256, 0, stream>>>(candKey, candIdx, cnt, sel, eqI);
    k_rank<<<1, 1024, 0, stream>>>(sel, eqI, cnt, boxes, rboxes, rvals, rlabel, out);
    k_nms<<<80, 64, 0, stream>>>(rboxes, rvals, rlabel, out);
}

// Round 11
// 178.324 us; speedup vs baseline: 1.3330x; 1.0691x over previous
//
#include <hip/hip_runtime.h>

#pragma clang fp contract(off)

typedef unsigned int u32;
typedef unsigned long long u64;
typedef long long i64;

#define N_ROWS 32768
#define NCLS 81
#define TOPK 4096
#define MAXCAND 327680
#define EQCAP 8192
#define IMGW_M1 1332.0f
#define IMGH_M1 799.0f

// k_cand geometry: 8 threads/row, 32 rows/block, 1024 blocks
#define CAND_THREADS 256
#define RPB 32
#define CAND_GRID (N_ROWS / RPB)          // 1024
#define CPT 11
#define BLK_CAND_CAP 640                  // 32 rows * <=19 cand/row = 608 max
#define ROW_F4 ((RPB * NCLS) / 4)         // 648 float4 per block slice (exactly)

// level-1 bins: f32 bits of p in (0.05, 1.0] -> hi16 in [0x3D4C, 0x3F80]
#define H1_BASE 0x3D4Cu
#define H1_BINS 576
#define HIST1_GRID 64

#define COLL_GRID 512
#define COLL_CAP 640

// k_nms LDS staging cap (per-class member count; avg ~51, cap 2048 is >>7 sigma)
#define MCAP 2048

// fast f64 exp for d <= 0 (clamped at -45). Cody-Waite + Taylor-13.
// Relative error ~3e-16 — decisions have >= f32-ulp (6e-8) margins.
__device__ inline double fast_exp_neg(double d) {
    if (d < -45.0) return 0.0;
    const double L2E    = 1.4426950408889634074;
    const double LN2_HI = 6.93147180369123816490e-01;
    const double LN2_LO = 1.90821492927058770002e-10;
    double n = __builtin_rint(d * L2E);
    double r = __builtin_fma(-n, LN2_HI, d);
    r = __builtin_fma(-n, LN2_LO, r);
    double p = 1.0 / 6227020800.0;
    p = __builtin_fma(p, r, 1.0 / 479001600.0);
    p = __builtin_fma(p, r, 1.0 / 39916800.0);
    p = __builtin_fma(p, r, 1.0 / 3628800.0);
    p = __builtin_fma(p, r, 1.0 / 362880.0);
    p = __builtin_fma(p, r, 1.0 / 40320.0);
    p = __builtin_fma(p, r, 1.0 / 5040.0);
    p = __builtin_fma(p, r, 1.0 / 720.0);
    p = __builtin_fma(p, r, 1.0 / 120.0);
    p = __builtin_fma(p, r, 1.0 / 24.0);
    p = __builtin_fma(p, r, 1.0 / 6.0);
    p = __builtin_fma(p, r, 0.5);
    p = __builtin_fma(p, r, 1.0);
    p = __builtin_fma(p, r, 1.0);
    i64 ni = (i64)n;
    double sc = __longlong_as_double((i64)(1023 + ni) << 52);
    return p * sc;
}

// softmax + threshold + DENSE compaction (block-local staging, one global
// atomic per block). Arithmetic identical to passing R9 -> bit-identical.
__global__ void __launch_bounds__(256) k_cand(const float* __restrict__ x,
                                              u32* __restrict__ candKey,
                                              u32* __restrict__ candIdx,
                                              u32* __restrict__ cnt) {
    __shared__ float4 lx4[ROW_F4];
    __shared__ u32 lK[BLK_CAND_CAP];
    __shared__ u32 lI[BLK_CAND_CAP];
    __shared__ u32 lcnt;
    __shared__ u32 gbaseSh;
    float* lx = (float*)lx4;
    const int t = threadIdx.x;
    if (t == 0) lcnt = 0;

    const float4* xv = (const float4*)x + (size_t)blockIdx.x * ROW_F4;
    for (int i = t; i < ROW_F4; i += CAND_THREADS) lx4[i] = xv[i];
    __syncthreads();

    const int rl = t >> 3;
    const int q = t & 7;
    const int c0 = q * 10;
    const int cEff = (q == 7) ? 11 : 10;
    const int row = blockIdx.x * RPB + rl;
    const float* xr = lx + rl * NCLS;

    float v[CPT];
    #pragma unroll
    for (int i = 0; i < CPT; i++) v[i] = (i < cEff) ? xr[c0 + i] : -1.0e30f;

    float m = v[0];
    #pragma unroll
    for (int i = 1; i < CPT; i++) m = fmaxf(m, v[i]);
    m = fmaxf(m, __shfl_xor(m, 1));
    m = fmaxf(m, __shfl_xor(m, 2));
    m = fmaxf(m, __shfl_xor(m, 4));

    double s = 0.0;
    #pragma unroll
    for (int i = 0; i < CPT; i++) {
        if (i < cEff) {
            float d = v[i] - m;
            s += fast_exp_neg((double)d);
        }
    }
    s += __shfl_xor(s, 1);
    s += __shfl_xor(s, 2);
    s += __shfl_xor(s, 4);

    const double THRMID = (double)0.05f + 0x1.0p-29;
    double ethr = THRMID * s;
    #pragma unroll
    for (int i = 0; i < CPT; i++) {
        int c = c0 + i;
        if (i < cEff && c != 0) {
            float d = v[i] - m;
            double e = fast_exp_neg((double)d);
            if (e > ethr) {
                float pf = (float)(e / s);
                u32 slot = atomicAdd(&lcnt, 1u);
                lK[slot] = __float_as_uint(pf);
                lI[slot] = (u32)(row * NCLS + c);
            }
        }
    }
    __syncthreads();
    u32 tot = lcnt;
    if (t == 0) gbaseSh = tot ? atomicAdd(&cnt[0], tot) : 0u;
    __syncthreads();
    u32 gbase = gbaseSh;
    for (u32 i = t; i < tot; i += CAND_THREADS) {
        u32 g = gbase + i;
        if (g < MAXCAND) {
            candKey[g] = lK[i];
            candIdx[g] = lI[i];
        }
    }
}

// DENSE grid-stride level-1 histogram -> atomic-free partial slices
__global__ void __launch_bounds__(256) k_hist1(const u32* __restrict__ candKey,
                                               const u32* __restrict__ cnt,
                                               u32* __restrict__ hist1p) {
    __shared__ u32 lh[H1_BINS];
    int t = threadIdx.x;
    for (int i = t; i < H1_BINS; i += 256) lh[i] = 0;
    __syncthreads();
    u32 n = cnt[0] < (u32)MAXCAND ? cnt[0] : (u32)MAXCAND;
    u32 stride = HIST1_GRID * 256;
    for (u32 i = blockIdx.x * 256 + t; i < n; i += stride) {
        u32 b = (candKey[i] >> 16) - H1_BASE;
        if (b < (u32)H1_BINS) atomicAdd(&lh[b], 1u);
    }
    __syncthreads();
    u32 ob = blockIdx.x * H1_BINS;
    for (int i = t; i < H1_BINS; i += 256) hist1p[ob + i] = lh[i];
}

// fused cutoff finder, all-LDS, dense pipelined scans
__global__ void __launch_bounds__(1024) k_mid(const u32* __restrict__ candKey,
                                              const u32* __restrict__ hist1p,
                                              u32* __restrict__ cnt) {
    __shared__ u32 cs[1024];
    __shared__ u32 h2[4096];
    __shared__ u32 h3[16];
    __shared__ u32 sB, sAcc, sB2, sAcc2, sFound;
    int t = threadIdx.x;
    if (t == 0) sFound = 0;
    if (t == 1) { cnt[1] = 0; cnt[2] = 0; }
    u32 s1 = 0;
    if (t < H1_BINS) {
        for (int j = 0; j < HIST1_GRID; j++) s1 += hist1p[j * H1_BINS + t];
    }
    cs[t] = (t < H1_BINS) ? s1 : 0u;
    for (int i = t; i < 4096; i += 1024) h2[i] = 0;
    if (t < 16) h3[t] = 0;
    __syncthreads();
    for (int d = 1; d < 1024; d <<= 1) {
        u32 v = (t + d < 1024) ? cs[t + d] : 0u;
        __syncthreads();
        cs[t] += v;
        __syncthreads();
    }
    {
        u32 S_t = cs[t];
        u32 S_next = (t < 1023) ? cs[t + 1] : 0u;
        if (S_next < TOPK && S_t >= TOPK) { sB = (u32)t; sAcc = S_next; sFound = 1; }
    }
    __syncthreads();
    if (!sFound) {
        if (t == 0) { cnt[5] = 0u; cnt[6] = 0u; }
        return;
    }
    const u32 Bhi = sB + H1_BASE;
    const u32 n = cnt[0] < (u32)MAXCAND ? cnt[0] : (u32)MAXCAND;
    for (u32 i = t; i < n; i += 1024) {
        u32 k = candKey[i];
        if ((k >> 16) == Bhi) atomicAdd(&h2[(k >> 4) & 0xFFFu], 1u);
    }
    __syncthreads();
    u32 c4 = h2[4 * t] + h2[4 * t + 1] + h2[4 * t + 2] + h2[4 * t + 3];
    __syncthreads();
    cs[t] = c4;
    __syncthreads();
    for (int d = 1; d < 1024; d <<= 1) {
        u32 v = (t + d < 1024) ? cs[t + d] : 0u;
        __syncthreads();
        cs[t] += v;
        __syncthreads();
    }
    {
        u32 C = sAcc;
        u32 S_t = C + cs[t];
        u32 S_next = C + ((t < 1023) ? cs[t + 1] : 0u);
        if (S_next < TOPK && S_t >= TOPK) {
            u32 acc = S_next;
            int b2 = 4 * t;
            for (int b = 4 * t + 3; b >= 4 * t; b--) {
                u32 h = h2[b];
                if (acc + h >= TOPK) { b2 = b; break; }
                acc += h;
            }
            sB2 = (u32)b2; sAcc2 = acc;
        }
    }
    __syncthreads();
    const u32 pre28 = (Bhi << 12) | sB2;
    for (u32 i = t; i < n; i += 1024) {
        u32 k = candKey[i];
        if ((k >> 4) == pre28) atomicAdd(&h3[k & 0xFu], 1u);
    }
    __syncthreads();
    if (t == 0) {
        u32 acc = sAcc2;
        int L = 0;
        for (int b = 15; b >= 0; b--) {
            u32 h = h3[b];
            if (acc + h >= TOPK) { L = b; break; }
            acc += h;
        }
        cnt[5] = (pre28 << 4) | (u32)L;
        cnt[6] = TOPK - acc;
    }
}

// block-aggregated collect over dense chunks
__global__ void __launch_bounds__(256) k_collect(const u32* __restrict__ candKey,
                                                 const u32* __restrict__ candIdx,
                                                 u32* __restrict__ cnt,
                                                 u64* __restrict__ sel,
                                                 u32* __restrict__ eqI) {
    __shared__ u64 sStage[COLL_CAP];
    __shared__ u32 eStage[COLL_CAP];
    __shared__ u32 sc, ec, sb, eb;
    int t = threadIdx.x;
    if (t == 0) { sc = 0; ec = 0; }
    __syncthreads();
    u32 n = cnt[0] < (u32)MAXCAND ? cnt[0] : (u32)MAXCAND;
    u32 chunk = (n + COLL_GRID - 1) / COLL_GRID;
    u32 lo = blockIdx.x * chunk;
    u32 hi = lo + chunk; if (hi > n) hi = n;
    u32 cut = cnt[5];
    for (u32 i = lo + t; i < hi; i += 256) {
        u32 k = candKey[i];
        if (k > cut) {
            u32 p = atomicAdd(&sc, 1u);
            sStage[p] = ((u64)k << 32) | (u64)(0xFFFFFFFFu - candIdx[i]);
        } else if (k == cut) {
            u32 e2 = atomicAdd(&ec, 1u);
            eStage[e2] = candIdx[i];
        }
    }
    __syncthreads();
    if (t == 0) {
        sb = sc ? atomicAdd(&cnt[1], sc) : 0u;
        eb = ec ? atomicAdd(&cnt[2], ec) : 0u;
    }
    __syncthreads();
    for (u32 i = t; i < sc; i += 256) { u32 g = sb + i; if (g < TOPK) sel[g] = sStage[i]; }
    for (u32 i = t; i < ec; i += 256) { u32 g = eb + i; if (g < EQCAP) eqI[g] = eStage[i]; }
}

// counting-rank: exact permutation, tail-only zero
__global__ void __launch_bounds__(1024) k_rank(const u64* __restrict__ sel,
                                               const u32* __restrict__ eqI,
                                               const u32* __restrict__ cnt,
                                               const float* __restrict__ boxes,
                                               float* __restrict__ rboxes, float* __restrict__ rvals,
                                               int* __restrict__ rlabel, float* __restrict__ out) {
    __shared__ u64 binned[TOPK];
    __shared__ u32 hist[H1_BINS];
    __shared__ u32 base[H1_BINS];
    __shared__ u32 cur[H1_BINS];
    __shared__ u32 cs[1024];
    int t = threadIdx.x;
    u32 nsel = cnt[1] < (u32)TOPK ? cnt[1] : (u32)TOPK;
    u32 m = cnt[2] < (u32)EQCAP ? cnt[2] : (u32)EQCAP;
    u32 need = cnt[6];
    if (nsel + need > (u32)TOPK) need = TOPK - nsel;
    u32 cut = cnt[5];
    u32 covered = nsel + need;
    for (u32 r = covered + t; r < TOPK; r += 1024) {
        rboxes[r * 4 + 0] = 0; rboxes[r * 4 + 1] = 0;
        rboxes[r * 4 + 2] = 0; rboxes[r * 4 + 3] = 0;
        rvals[r] = 0.0f; rlabel[r] = 0;
        out[TOPK * 5 + r] = 0.0f;
        out[TOPK * 6 + r] = 0.0f;
        float* d = out + (size_t)r * 5;
        d[0] = 0; d[1] = 0; d[2] = 0; d[3] = 0; d[4] = 0;
    }
    for (int i = t; i < H1_BINS; i += 1024) { hist[i] = 0; cur[i] = 0; }
    __syncthreads();
    for (u32 i = t; i < nsel; i += 1024) {
        u32 b = (u32)(sel[i] >> 48) - H1_BASE;
        if (b >= (u32)H1_BINS) b = 0;
        atomicAdd(&hist[b], 1u);
    }
    __syncthreads();
    cs[t] = (t < H1_BINS) ? hist[t] : 0u;
    __syncthreads();
    for (int d = 1; d < 1024; d <<= 1) {
        u32 v = (t + d < 1024) ? cs[t + d] : 0u;
        __syncthreads();
        cs[t] += v;
        __syncthreads();
    }
    if (t < H1_BINS) base[t] = (t + 1 < 1024) ? cs[t + 1] : 0u;
    __syncthreads();
    for (u32 i = t; i < nsel; i += 1024) {
        u64 c = sel[i];
        u32 b = (u32)(c >> 48) - H1_BASE;
        if (b >= (u32)H1_BINS) b = 0;
        u32 p = base[b] + atomicAdd(&cur[b], 1u);
        if (p < (u32)TOPK) binned[p] = c;
    }
    __syncthreads();

    for (u32 p = t; p < nsel; p += 1024) {
        u64 c = binned[p];
        u32 b = (u32)(c >> 48) - H1_BASE;
        if (b >= (u32)H1_BINS) b = 0;
        u32 s0 = base[b], cb = hist[b];
        u32 r = s0;
        for (u32 qq = s0; qq < s0 + cb; qq++) r += (binned[qq] > c) ? 1u : 0u;
        u32 idx = 0xFFFFFFFFu - (u32)(c & 0xFFFFFFFFull);
        float val = __uint_as_float((u32)(c >> 32));
        u32 bi = idx / NCLS;
        u32 lab = idx % NCLS;
        const float* bp = boxes + (size_t)bi * 4;
        float x1 = fminf(fmaxf(bp[0], 0.0f), IMGW_M1);
        float y1 = fminf(fmaxf(bp[1], 0.0f), IMGH_M1);
        float x2 = fminf(fmaxf(bp[2], 0.0f), IMGW_M1);
        float y2 = fminf(fmaxf(bp[3], 0.0f), IMGH_M1);
        rboxes[r * 4 + 0] = x1; rboxes[r * 4 + 1] = y1;
        rboxes[r * 4 + 2] = x2; rboxes[r * 4 + 3] = y2;
        rvals[r] = val;
        rlabel[r] = (int)lab;
        out[TOPK * 5 + r] = (float)lab;
    }
    for (u32 j = t; j < m; j += 1024) {
        u32 v = eqI[j];
        u32 rho = 0;
        for (u32 k = 0; k < m; k++) rho += (eqI[k] < v) ? 1u : 0u;
        if (rho < need) {
            u32 r = nsel + rho;
            float val = __uint_as_float(cut);
            u32 bi = v / NCLS;
            u32 lab = v % NCLS;
            const float* bp = boxes + (size_t)bi * 4;
            float x1 = fminf(fmaxf(bp[0], 0.0f), IMGW_M1);
            float y1 = fminf(fmaxf(bp[1], 0.0f), IMGH_M1);
            float x2 = fminf(fmaxf(bp[2], 0.0f), IMGW_M1);
            float y2 = fminf(fmaxf(bp[3], 0.0f), IMGH_M1);
            rboxes[r * 4 + 0] = x1; rboxes[r * 4 + 1] = y1;
            rboxes[r * 4 + 2] = x2; rboxes[r * 4 + 3] = y2;
            rvals[r] = val;
            rlabel[r] = (int)lab;
            out[TOPK * 5 + r] = (float)lab;
        }
    }
}

// ---- tiled bitmask greedy NMS, one block (256 thr) per class ----
// colmask[s] = ballot of members s suppresses (j > s, iou > 0.5) — built via
// per-step __ballot so the greedy chain ORs the CORRECT (column) set.
// IoU math is symmetric in operand order -> bit-identical to reference iou_gt.
// Class-local suppression is exact (label*4096 offset separates classes).

__device__ inline float4 nms_box(u32 g, const float4* __restrict__ boxL,
                                 const float* __restrict__ rboxes,
                                 const unsigned short* __restrict__ memRank, float off) {
    if (g < (u32)MCAP) return boxL[g];
    float4 b = ((const float4*)rboxes)[memRank[g]];     // fallback: never in practice
    return make_float4(b.x + off, b.y + off, b.z + off, b.w + off);
}
__device__ inline float nms_area(u32 g, const float* __restrict__ areaL, float4 b) {
    if (g < (u32)MCAP) return areaL[g];
    return (b.z - b.x) * (b.w - b.y);
}

__global__ void __launch_bounds__(256) k_nms(const float* __restrict__ rboxes,
                                             const float* __restrict__ rvals,
                                             const int* __restrict__ rlabel,
                                             float* __restrict__ out) {
    int c = blockIdx.x + 1;                     // labels 1..80
    __shared__ float4 boxL[MCAP];               // offset boxes (32 KB)
    __shared__ float areaL[MCAP];               // 8 KB
    __shared__ unsigned short memRank[TOPK];    // 8 KB
    __shared__ u32 cc[64];
    __shared__ u32 baseC[64];
    __shared__ u64 removedW[64];
    __shared__ u32 mTotSh;
    const int t = threadIdx.x;
    const int w = t >> 6, lane = t & 63;
    const u64 laneLT = ((u64)1 << lane) - 1;
    const float off = (float)c * 4096.0f;       // reference's f32 offset rounding

    // phase A: per-64-chunk counts (wave w handles chunks 4*it + w)
    for (int it = 0; it < 16; it++) {
        int chunk = it * 4 + w;
        int r = chunk * 64 + lane;
        u64 mask = __ballot(rlabel[r] == c);
        if (lane == 0) cc[chunk] = (u32)__popcll(mask);
    }
    __syncthreads();
    // phase B: exclusive scan of 64 chunk counts (wave 0, shfl_up)
    if (t < 64) {
        u32 v = cc[t];
        u32 inc = v;
        #pragma unroll
        for (int d = 1; d < 64; d <<= 1) {
            u32 o = __shfl_up(inc, d);
            if (lane >= d) inc += o;
        }
        baseC[t] = inc - v;
        if (t == 63) mTotSh = inc;
    }
    __syncthreads();
    const u32 m = mTotSh;
    // phase C: stable scatter + stage offset boxes/areas
    for (int it = 0; it < 16; it++) {
        int chunk = it * 4 + w;
        int r = chunk * 64 + lane;
        bool match = (rlabel[r] == c);
        u64 mask = __ballot(match);
        if (match) {
            u32 g = baseC[chunk] + (u32)__popcll(mask & laneLT);
            memRank[g] = (unsigned short)r;
            if (g < (u32)MCAP) {
                float4 b = ((const float4*)rboxes)[r];
                float bx1 = b.x + off, by1 = b.y + off;
                float bx2 = b.z + off, by2 = b.w + off;
                boxL[g] = make_float4(bx1, by1, bx2, by2);
                areaL[g] = (bx2 - bx1) * (by2 - by1);   // reference: area on offset boxes
            }
        }
    }
    __syncthreads();

    // NMS tiles: wave 0 only
    if (t < 64) {
        u32 nTiles = (m + 63) >> 6;
        for (u32 T = 0; T < nTiles; T++) {
            u32 tsize = m - T * 64; if (tsize > 64) tsize = 64;
            u32 g = T * 64 + (u32)lane;
            bool active = (u32)lane < tsize;
            float4 myB = make_float4(0, 0, 0, 0);
            float myA = 0.0f;
            if (active) {
                myB = nms_box(g, boxL, rboxes, memRank, off);
                myA = nms_area(g, areaL, myB);
            }
            // cross-tile suppression from kept members of earlier tiles
            bool supPrev = false;
            for (u32 P = 0; P < T; P++) {
                u64 remP = removedW[P];
                for (u32 s2 = 0; s2 < 64; s2++) {
                    if ((remP >> s2) & 1) continue;          // uniform
                    u32 p = P * 64 + s2;
                    float4 bs = nms_box(p, boxL, rboxes, memRank, off);
                    float as = nms_area(p, areaL, bs);
                    if (active) {
                        float iw = fmaxf(fminf(myB.z, bs.z) - fmaxf(myB.x, bs.x), 0.0f);
                        float ih = fmaxf(fminf(myB.w, bs.w) - fmaxf(myB.y, bs.y), 0.0f);
                        float inter = iw * ih;
                        float iou = inter / (as + myA - inter + 1e-9f);
                        supPrev |= (iou > 0.5f);
                    }
                }
            }
            // intra-tile COLUMN masks via ballot: colmask (held by lane s2) =
            // set of lanes j > s2 that member s2 suppresses
            u64 colmask = 0;
            for (u32 s2 = 0; s2 + 1 < tsize; s2++) {
                u32 p = T * 64 + s2;
                float4 bs = nms_box(p, boxL, rboxes, memRank, off);
                float as = nms_area(p, areaL, bs);
                bool sup = false;
                if (active && (u32)lane > s2) {
                    float iw = fmaxf(fminf(myB.z, bs.z) - fmaxf(myB.x, bs.x), 0.0f);
                    float ih = fmaxf(fminf(myB.w, bs.w) - fmaxf(myB.y, bs.y), 0.0f);
                    float inter = iw * ih;
                    float iou = inter / (as + myA - inter + 1e-9f);
                    sup = (iou > 0.5f);
                }
                u64 ball = __ballot(sup);
                if ((u32)lane == s2) colmask = ball;
            }
            // greedy scan: shuffle chain over COLUMN masks
            u64 rem = __ballot(supPrev && active);
            for (u32 s2 = 0; s2 < tsize; s2++) {
                u64 col = __shfl(colmask, (int)s2);
                if (!((rem >> s2) & 1)) rem |= col;
            }
            if (lane == 0) removedW[T] = rem;
        }
    }
    __syncthreads();

    // output: all 256 threads
    for (u32 q = t; q < m; q += 256) {
        bool keep = !((removedW[q >> 6] >> (q & 63)) & 1);
        int r = memRank[q];
        out[TOPK * 6 + r] = keep ? 1.0f : 0.0f;
        float* d = out + (size_t)r * 5;
        if (keep) {
            float4 b = ((const float4*)rboxes)[r];
            d[0] = b.x; d[1] = b.y; d[2] = b.z; d[3] = b.w;
            d[4] = rvals[r];
        } else {
            d[0] = 0; d[1] = 0; d[2] = 0; d[3] = 0; d[4] = 0;
        }
    }
}

extern "C" void kernel_launch(void* const* d_in, const int* in_sizes, int n_in,
                              void* d_out, int out_size, void* d_ws, size_t ws_size,
                              hipStream_t stream) {
    const float* x = (const float*)d_in[0];
    const float* boxes = (const float*)d_in[1];
    float* out = (float*)d_out;

    u32* W = (u32*)d_ws;
    u32* cnt = W;                                          // 16
    u32* hist1p = W + 16;                                  // 64*576 = 36864
    u32* candKey = W + 16 + 36864;                         // MAXCAND
    u32* candIdx = candKey + MAXCAND;                      // MAXCAND
    u64* sel = (u64*)(candIdx + MAXCAND);                  // 4096 u64 (8B aligned)
    u32* eqI = (u32*)(sel + TOPK);                         // 8192
    float* rboxes = (float*)(eqI + EQCAP);                 // 16384
    float* rvals = rboxes + 4 * TOPK;                      // 4096
    int* rlabel = (int*)(rvals + TOPK);                    // 4096

    hipMemsetAsync(cnt, 0, 16 * sizeof(u32), stream);      // graph-capture-safe
    k_cand<<<CAND_GRID, CAND_THREADS, 0, stream>>>(x, candKey, candIdx, cnt);
    k_hist1<<<HIST1_GRID, 256, 0, stream>>>(candKey, cnt, hist1p);
    k_mid<<<1, 1024, 0, stream>>>(candKey, hist1p, cnt);
    k_collect<<<COLL_GRID, 256, 0, stream>>>(candKey, candIdx, cnt, sel, eqI);
    k_rank<<<1, 1024, 0, stream>>>(sel, eqI, cnt, boxes, rboxes, rvals, rlabel, out);
    k_nms<<<80, 256, 0, stream>>>(rboxes, rvals, rlabel, out);
}

// Round 12
// 170.091 us; speedup vs baseline: 1.3975x; 1.0484x over previous
//
#include <hip/hip_runtime.h>

#pragma clang fp contract(off)

typedef unsigned int u32;
typedef unsigned long long u64;
typedef long long i64;

#define N_ROWS 32768
#define NCLS 81
#define TOPK 4096
#define MAXCAND 327680
#define EQCAP 8192
#define IMGW_M1 1332.0f
#define IMGH_M1 799.0f

// k_cand geometry: 8 threads/row, 32 rows/block, 1024 blocks
#define CAND_THREADS 256
#define RPB 32
#define CAND_GRID (N_ROWS / RPB)          // 1024
#define CPT 11
#define BLK_CAND_CAP 640                  // 32 rows * <=19 cand/row = 608 max
#define ROW_F4 ((RPB * NCLS) / 4)         // 648 float4 per block slice (exactly)

// level-1 bins: f32 bits of p in (0.05, 1.0] -> hi16 in [0x3D4C, 0x3F80]
#define H1_BASE 0x3D4Cu
#define H1_BINS 576
#define H1_SLICES 64

#define COLL_GRID 512

// k_nms LDS staging cap
#define MCAP 2048

// fast f64 exp for d <= 0 (clamped at -45). Cody-Waite + Taylor-13.
// Relative error ~3e-16 — decisions have >= f32-ulp (6e-8) margins.
__device__ inline double fast_exp_neg(double d) {
    if (d < -45.0) return 0.0;
    const double L2E    = 1.4426950408889634074;
    const double LN2_HI = 6.93147180369123816490e-01;
    const double LN2_LO = 1.90821492927058770002e-10;
    double n = __builtin_rint(d * L2E);
    double r = __builtin_fma(-n, LN2_HI, d);
    r = __builtin_fma(-n, LN2_LO, r);
    double p = 1.0 / 6227020800.0;
    p = __builtin_fma(p, r, 1.0 / 479001600.0);
    p = __builtin_fma(p, r, 1.0 / 39916800.0);
    p = __builtin_fma(p, r, 1.0 / 3628800.0);
    p = __builtin_fma(p, r, 1.0 / 362880.0);
    p = __builtin_fma(p, r, 1.0 / 40320.0);
    p = __builtin_fma(p, r, 1.0 / 5040.0);
    p = __builtin_fma(p, r, 1.0 / 720.0);
    p = __builtin_fma(p, r, 1.0 / 120.0);
    p = __builtin_fma(p, r, 1.0 / 24.0);
    p = __builtin_fma(p, r, 1.0 / 6.0);
    p = __builtin_fma(p, r, 0.5);
    p = __builtin_fma(p, r, 1.0);
    p = __builtin_fma(p, r, 1.0);
    i64 ni = (i64)n;
    double sc = __longlong_as_double((i64)(1023 + ni) << 52);
    return p * sc;
}

// softmax + threshold + DENSE compaction + FUSED level-1 histogram.
// Block-local LDS hist merged into slice (blockIdx&63): per-address atomic
// depth <= 16 (benign; the R5 killer was ~500-deep single-array atomics).
// Decision arithmetic identical to passing R11 -> bit-identical.
__global__ void __launch_bounds__(256) k_cand(const float* __restrict__ x,
                                              u32* __restrict__ candKey,
                                              u32* __restrict__ candIdx,
                                              u32* __restrict__ cnt,
                                              u32* __restrict__ hist1p) {
    __shared__ float4 lx4[ROW_F4];
    __shared__ u32 lK[BLK_CAND_CAP];
    __shared__ u32 lI[BLK_CAND_CAP];
    __shared__ u32 lh[H1_BINS];
    __shared__ u32 lcnt;
    __shared__ u32 gbaseSh;
    float* lx = (float*)lx4;
    const int t = threadIdx.x;
    if (t == 0) lcnt = 0;
    for (int i = t; i < H1_BINS; i += CAND_THREADS) lh[i] = 0;

    const float4* xv = (const float4*)x + (size_t)blockIdx.x * ROW_F4;
    for (int i = t; i < ROW_F4; i += CAND_THREADS) lx4[i] = xv[i];
    __syncthreads();

    const int rl = t >> 3;
    const int q = t & 7;
    const int c0 = q * 10;
    const int cEff = (q == 7) ? 11 : 10;
    const int row = blockIdx.x * RPB + rl;
    const float* xr = lx + rl * NCLS;

    float v[CPT];
    #pragma unroll
    for (int i = 0; i < CPT; i++) v[i] = (i < cEff) ? xr[c0 + i] : -1.0e30f;

    float m = v[0];
    #pragma unroll
    for (int i = 1; i < CPT; i++) m = fmaxf(m, v[i]);
    m = fmaxf(m, __shfl_xor(m, 1));
    m = fmaxf(m, __shfl_xor(m, 2));
    m = fmaxf(m, __shfl_xor(m, 4));

    double s = 0.0;
    #pragma unroll
    for (int i = 0; i < CPT; i++) {
        if (i < cEff) {
            float d = v[i] - m;
            s += fast_exp_neg((double)d);
        }
    }
    s += __shfl_xor(s, 1);
    s += __shfl_xor(s, 2);
    s += __shfl_xor(s, 4);

    const double THRMID = (double)0.05f + 0x1.0p-29;
    double ethr = THRMID * s;
    #pragma unroll
    for (int i = 0; i < CPT; i++) {
        int c = c0 + i;
        if (i < cEff && c != 0) {
            float d = v[i] - m;
            double e = fast_exp_neg((double)d);
            if (e > ethr) {
                float pf = (float)(e / s);
                u32 slot = atomicAdd(&lcnt, 1u);
                lK[slot] = __float_as_uint(pf);
                lI[slot] = (u32)(row * NCLS + c);
            }
        }
    }
    __syncthreads();
    u32 tot = lcnt;
    if (t == 0) gbaseSh = tot ? atomicAdd(&cnt[0], tot) : 0u;
    // LDS histogram of this block's keys
    for (u32 i = t; i < tot; i += CAND_THREADS) {
        u32 b = (lK[i] >> 16) - H1_BASE;
        if (b < (u32)H1_BINS) atomicAdd(&lh[b], 1u);
    }
    __syncthreads();
    u32 gbase = gbaseSh;
    for (u32 i = t; i < tot; i += CAND_THREADS) {
        u32 g = gbase + i;
        if (g < MAXCAND) {
            candKey[g] = lK[i];
            candIdx[g] = lI[i];
        }
    }
    // merge nonzero bins into slice (blockIdx & 63): depth <= 16 per address
    u32 ob = (blockIdx.x & (H1_SLICES - 1)) * H1_BINS;
    for (int i = t; i < H1_BINS; i += CAND_THREADS) {
        u32 h = lh[i];
        if (h) atomicAdd(&hist1p[ob + i], h);
    }
}

// fused cutoff finder, all-LDS, dense pipelined scans.
// Publishes: cnt[5]=cutKey, cnt[6]=need, cnt[1]=nsel, cnt[3]=B, sufG[0..576]
__global__ void __launch_bounds__(1024) k_mid(const u32* __restrict__ candKey,
                                              const u32* __restrict__ hist1p,
                                              u32* __restrict__ cnt,
                                              u32* __restrict__ sufG) {
    __shared__ u32 cs[1024];
    __shared__ u32 h2[4096];
    __shared__ u32 h3[16];
    __shared__ u32 sB, sAcc, sB2, sAcc2, sFound;
    int t = threadIdx.x;
    if (t == 0) sFound = 0;
    u32 s1 = 0;
    if (t < H1_BINS) {
        for (int j = 0; j < H1_SLICES; j++) s1 += hist1p[j * H1_BINS + t];
    }
    cs[t] = (t < H1_BINS) ? s1 : 0u;
    for (int i = t; i < 4096; i += 1024) h2[i] = 0;
    if (t < 16) h3[t] = 0;
    __syncthreads();
    for (int d = 1; d < 1024; d <<= 1) {          // inclusive suffix sum
        u32 v = (t + d < 1024) ? cs[t + d] : 0u;
        __syncthreads();
        cs[t] += v;
        __syncthreads();
    }
    if (t < 577) sufG[t] = cs[t];                 // cs[576] == 0 naturally
    {
        u32 S_t = cs[t];
        u32 S_next = (t < 1023) ? cs[t + 1] : 0u;
        if (S_next < TOPK && S_t >= TOPK) { sB = (u32)t; sAcc = S_next; sFound = 1; }
    }
    __syncthreads();
    if (!sFound) {                                // degenerate: < TOPK candidates
        if (t < 577) sufG[t] = 0u;
        if (t == 0) { cnt[5] = 0xFFFFFFFFu; cnt[6] = 0u; cnt[1] = 0u; cnt[3] = 0u; }
        return;
    }
    const u32 Bhi = sB + H1_BASE;
    const u32 n = cnt[0] < (u32)MAXCAND ? cnt[0] : (u32)MAXCAND;
    for (u32 i = t; i < n; i += 1024) {
        u32 k = candKey[i];
        if ((k >> 16) == Bhi) atomicAdd(&h2[(k >> 4) & 0xFFFu], 1u);
    }
    __syncthreads();
    u32 c4 = h2[4 * t] + h2[4 * t + 1] + h2[4 * t + 2] + h2[4 * t + 3];
    __syncthreads();
    cs[t] = c4;
    __syncthreads();
    for (int d = 1; d < 1024; d <<= 1) {
        u32 v = (t + d < 1024) ? cs[t + d] : 0u;
        __syncthreads();
        cs[t] += v;
        __syncthreads();
    }
    {
        u32 C = sAcc;
        u32 S_t = C + cs[t];
        u32 S_next = C + ((t < 1023) ? cs[t + 1] : 0u);
        if (S_next < TOPK && S_t >= TOPK) {
            u32 acc = S_next;
            int b2 = 4 * t;
            for (int b = 4 * t + 3; b >= 4 * t; b--) {
                u32 h = h2[b];
                if (acc + h >= TOPK) { b2 = b; break; }
                acc += h;
            }
            sB2 = (u32)b2; sAcc2 = acc;
        }
    }
    __syncthreads();
    const u32 pre28 = (Bhi << 12) | sB2;
    for (u32 i = t; i < n; i += 1024) {
        u32 k = candKey[i];
        if ((k >> 4) == pre28) atomicAdd(&h3[k & 0xFu], 1u);
    }
    __syncthreads();
    if (t == 0) {
        u32 acc = sAcc2;
        int L = 0;
        for (int b = 15; b >= 0; b--) {
            u32 h = h3[b];
            if (acc + h >= TOPK) { L = b; break; }
            acc += h;
        }
        cnt[5] = (pre28 << 4) | (u32)L;           // exact cutoff key
        cnt[6] = TOPK - acc;                      // take from ==cutoff set
        cnt[1] = acc;                             // nsel (# keys > cut)
        cnt[3] = sB;                              // cutoff bin index
    }
}

// scatter selected candidates directly into per-bin segments of sel[]
__global__ void __launch_bounds__(256) k_collect(const u32* __restrict__ candKey,
                                                 const u32* __restrict__ candIdx,
                                                 u32* __restrict__ cnt,
                                                 const u32* __restrict__ sufG,
                                                 u32* __restrict__ binCur,
                                                 u64* __restrict__ sel,
                                                 u32* __restrict__ eqI) {
    u32 n = cnt[0] < (u32)MAXCAND ? cnt[0] : (u32)MAXCAND;
    u32 cut = cnt[5];
    u32 stride = COLL_GRID * 256;
    for (u32 i = blockIdx.x * 256 + threadIdx.x; i < n; i += stride) {
        u32 k = candKey[i];
        if (k > cut) {
            u32 b = (k >> 16) - H1_BASE;          // b >= B guaranteed (k > cut)
            u32 pos = sufG[b + 1] + atomicAdd(&binCur[b], 1u);
            if (pos < (u32)TOPK)
                sel[pos] = ((u64)k << 32) | (u64)(0xFFFFFFFFu - candIdx[i]);
        } else if (k == cut) {
            u32 e2 = atomicAdd(&cnt[2], 1u);
            if (e2 < (u32)EQCAP) eqI[e2] = candIdx[i];
        }
    }
}

// distributed ranking: one block per level-1 bin (segment already grouped in
// sel[]); within-bin quadratic rank over composite (value-desc, idx-asc).
// Block 576 handles ==cutoff entries (idx-asc, take `need`) + degenerate tail.
__global__ void __launch_bounds__(256) k_binrank(const u64* __restrict__ sel,
                                                 const u32* __restrict__ eqI,
                                                 const u32* __restrict__ cnt,
                                                 const u32* __restrict__ sufG,
                                                 const float* __restrict__ boxes,
                                                 float* __restrict__ rboxes,
                                                 float* __restrict__ rvals,
                                                 int* __restrict__ rlabel,
                                                 float* __restrict__ out) {
    const int t = threadIdx.x;
    const u32 nsel = cnt[1] < (u32)TOPK ? cnt[1] : (u32)TOPK;

    if (blockIdx.x == H1_BINS) {                  // eq + tail block
        u32 m = cnt[2] < (u32)EQCAP ? cnt[2] : (u32)EQCAP;
        u32 need = cnt[6];
        if (nsel + need > (u32)TOPK) need = TOPK - nsel;
        u32 cut = cnt[5];
        u32 covered = nsel + need;
        for (u32 r = covered + t; r < TOPK; r += 256) {   // degenerate-only
            rboxes[r * 4 + 0] = 0; rboxes[r * 4 + 1] = 0;
            rboxes[r * 4 + 2] = 0; rboxes[r * 4 + 3] = 0;
            rvals[r] = 0.0f; rlabel[r] = 0;
            out[TOPK * 5 + r] = 0.0f;
            out[TOPK * 6 + r] = 0.0f;
            float* d = out + (size_t)r * 5;
            d[0] = 0; d[1] = 0; d[2] = 0; d[3] = 0; d[4] = 0;
        }
        for (u32 j = t; j < m; j += 256) {
            u32 v = eqI[j];
            u32 rho = 0;
            for (u32 k = 0; k < m; k++) rho += (eqI[k] < v) ? 1u : 0u;  // unique
            if (rho < need) {
                u32 r = nsel + rho;
                float val = __uint_as_float(cut);
                u32 bi = v / NCLS;
                u32 lab = v % NCLS;
                const float* bp = boxes + (size_t)bi * 4;
                float x1 = fminf(fmaxf(bp[0], 0.0f), IMGW_M1);
                float y1 = fminf(fmaxf(bp[1], 0.0f), IMGH_M1);
                float x2 = fminf(fmaxf(bp[2], 0.0f), IMGW_M1);
                float y2 = fminf(fmaxf(bp[3], 0.0f), IMGH_M1);
                rboxes[r * 4 + 0] = x1; rboxes[r * 4 + 1] = y1;
                rboxes[r * 4 + 2] = x2; rboxes[r * 4 + 3] = y2;
                rvals[r] = val;
                rlabel[r] = (int)lab;
                out[TOPK * 5 + r] = (float)lab;
            }
        }
        return;
    }

    __shared__ u64 seg[TOPK];                     // 32 KB (worst segment = nsel)
    const u32 b = blockIdx.x;
    const u32 B = cnt[3];
    if (b < B) return;
    u32 start = sufG[b + 1];
    u32 end = (b == B) ? nsel : sufG[b];
    if (end > (u32)TOPK) end = TOPK;
    if (start >= end) return;
    u32 len = end - start;
    for (u32 i = t; i < len; i += 256) seg[i] = sel[start + i];
    __syncthreads();
    for (u32 i = t; i < len; i += 256) {
        u64 c = seg[i];
        u32 r = start;
        for (u32 j = 0; j < len; j++) r += (seg[j] > c) ? 1u : 0u;
        u32 idx = 0xFFFFFFFFu - (u32)(c & 0xFFFFFFFFull);
        float val = __uint_as_float((u32)(c >> 32));
        u32 bi = idx / NCLS;
        u32 lab = idx % NCLS;
        const float* bp = boxes + (size_t)bi * 4;
        float x1 = fminf(fmaxf(bp[0], 0.0f), IMGW_M1);
        float y1 = fminf(fmaxf(bp[1], 0.0f), IMGH_M1);
        float x2 = fminf(fmaxf(bp[2], 0.0f), IMGW_M1);
        float y2 = fminf(fmaxf(bp[3], 0.0f), IMGH_M1);
        rboxes[r * 4 + 0] = x1; rboxes[r * 4 + 1] = y1;
        rboxes[r * 4 + 2] = x2; rboxes[r * 4 + 3] = y2;
        rvals[r] = val;
        rlabel[r] = (int)lab;
        out[TOPK * 5 + r] = (float)lab;           // labels (unmasked in reference)
    }
}

// ---- tiled bitmask greedy NMS (R11, verified) ----
__device__ inline float4 nms_box(u32 g, const float4* __restrict__ boxL,
                                 const float* __restrict__ rboxes,
                                 const unsigned short* __restrict__ memRank, float off) {
    if (g < (u32)MCAP) return boxL[g];
    float4 b = ((const float4*)rboxes)[memRank[g]];
    return make_float4(b.x + off, b.y + off, b.z + off, b.w + off);
}
__device__ inline float nms_area(u32 g, const float* __restrict__ areaL, float4 b) {
    if (g < (u32)MCAP) return areaL[g];
    return (b.z - b.x) * (b.w - b.y);
}

__global__ void __launch_bounds__(256) k_nms(const float* __restrict__ rboxes,
                                             const float* __restrict__ rvals,
                                             const int* __restrict__ rlabel,
                                             float* __restrict__ out) {
    int c = blockIdx.x + 1;                     // labels 1..80
    __shared__ float4 boxL[MCAP];
    __shared__ float areaL[MCAP];
    __shared__ unsigned short memRank[TOPK];
    __shared__ u32 cc[64];
    __shared__ u32 baseC[64];
    __shared__ u64 removedW[64];
    __shared__ u32 mTotSh;
    const int t = threadIdx.x;
    const int w = t >> 6, lane = t & 63;
    const u64 laneLT = ((u64)1 << lane) - 1;
    const float off = (float)c * 4096.0f;

    for (int it = 0; it < 16; it++) {
        int chunk = it * 4 + w;
        int r = chunk * 64 + lane;
        u64 mask = __ballot(rlabel[r] == c);
        if (lane == 0) cc[chunk] = (u32)__popcll(mask);
    }
    __syncthreads();
    if (t < 64) {
        u32 v = cc[t];
        u32 inc = v;
        #pragma unroll
        for (int d = 1; d < 64; d <<= 1) {
            u32 o = __shfl_up(inc, d);
            if (lane >= d) inc += o;
        }
        baseC[t] = inc - v;
        if (t == 63) mTotSh = inc;
    }
    __syncthreads();
    const u32 m = mTotSh;
    for (int it = 0; it < 16; it++) {
        int chunk = it * 4 + w;
        int r = chunk * 64 + lane;
        bool match = (rlabel[r] == c);
        u64 mask = __ballot(match);
        if (match) {
            u32 g = baseC[chunk] + (u32)__popcll(mask & laneLT);
            memRank[g] = (unsigned short)r;
            if (g < (u32)MCAP) {
                float4 b = ((const float4*)rboxes)[r];
                float bx1 = b.x + off, by1 = b.y + off;
                float bx2 = b.z + off, by2 = b.w + off;
                boxL[g] = make_float4(bx1, by1, bx2, by2);
                areaL[g] = (bx2 - bx1) * (by2 - by1);
            }
        }
    }
    __syncthreads();

    if (t < 64) {
        u32 nTiles = (m + 63) >> 6;
        for (u32 T = 0; T < nTiles; T++) {
            u32 tsize = m - T * 64; if (tsize > 64) tsize = 64;
            u32 g = T * 64 + (u32)lane;
            bool active = (u32)lane < tsize;
            float4 myB = make_float4(0, 0, 0, 0);
            float myA = 0.0f;
            if (active) {
                myB = nms_box(g, boxL, rboxes, memRank, off);
                myA = nms_area(g, areaL, myB);
            }
            bool supPrev = false;
            for (u32 P = 0; P < T; P++) {
                u64 remP = removedW[P];
                for (u32 s2 = 0; s2 < 64; s2++) {
                    if ((remP >> s2) & 1) continue;
                    u32 p = P * 64 + s2;
                    float4 bs = nms_box(p, boxL, rboxes, memRank, off);
                    float as = nms_area(p, areaL, bs);
                    if (active) {
                        float iw = fmaxf(fminf(myB.z, bs.z) - fmaxf(myB.x, bs.x), 0.0f);
                        float ih = fmaxf(fminf(myB.w, bs.w) - fmaxf(myB.y, bs.y), 0.0f);
                        float inter = iw * ih;
                        float iou = inter / (as + myA - inter + 1e-9f);
                        supPrev |= (iou > 0.5f);
                    }
                }
            }
            u64 colmask = 0;
            for (u32 s2 = 0; s2 + 1 < tsize; s2++) {
                u32 p = T * 64 + s2;
                float4 bs = nms_box(p, boxL, rboxes, memRank, off);
                float as = nms_area(p, areaL, bs);
                bool sup = false;
                if (active && (u32)lane > s2) {
                    float iw = fmaxf(fminf(myB.z, bs.z) - fmaxf(myB.x, bs.x), 0.0f);
                    float ih = fmaxf(fminf(myB.w, bs.w) - fmaxf(myB.y, bs.y), 0.0f);
                    float inter = iw * ih;
                    float iou = inter / (as + myA - inter + 1e-9f);
                    sup = (iou > 0.5f);
                }
                u64 ball = __ballot(sup);
                if ((u32)lane == s2) colmask = ball;
            }
            u64 rem = __ballot(supPrev && active);
            for (u32 s2 = 0; s2 < tsize; s2++) {
                u64 col = __shfl(colmask, (int)s2);
                if (!((rem >> s2) & 1)) rem |= col;
            }
            if (lane == 0) removedW[T] = rem;
        }
    }
    __syncthreads();

    for (u32 q = t; q < m; q += 256) {
        bool keep = !((removedW[q >> 6] >> (q & 63)) & 1);
        int r = memRank[q];
        out[TOPK * 6 + r] = keep ? 1.0f : 0.0f;
        float* d = out + (size_t)r * 5;
        if (keep) {
            float4 b = ((const float4*)rboxes)[r];
            d[0] = b.x; d[1] = b.y; d[2] = b.z; d[3] = b.w;
            d[4] = rvals[r];
        } else {
            d[0] = 0; d[1] = 0; d[2] = 0; d[3] = 0; d[4] = 0;
        }
    }
}

extern "C" void kernel_launch(void* const* d_in, const int* in_sizes, int n_in,
                              void* d_out, int out_size, void* d_ws, size_t ws_size,
                              hipStream_t stream) {
    const float* x = (const float*)d_in[0];
    const float* boxes = (const float*)d_in[1];
    float* out = (float*)d_out;

    u32* W = (u32*)d_ws;
    u32* cnt = W;                                          // 16
    u32* hist1p = W + 16;                                  // 64*576 = 36864
    u32* binCur = W + 16 + 36864;                          // 576
    u32* sufG = binCur + 576;                              // 584 (577 used)
    u32* candKey = sufG + 584;                             // MAXCAND
    u32* candIdx = candKey + MAXCAND;                      // MAXCAND
    u64* sel = (u64*)(candIdx + MAXCAND);                  // 4096 u64 (offset even -> 8B aligned)
    u32* eqI = (u32*)(sel + TOPK);                         // 8192
    float* rboxes = (float*)(eqI + EQCAP);                 // 16384
    float* rvals = rboxes + 4 * TOPK;                      // 4096
    int* rlabel = (int*)(rvals + TOPK);                    // 4096

    // zero: cnt + hist1p + binCur (contiguous, ~150 KB)
    hipMemsetAsync(W, 0, (16 + 36864 + 576) * sizeof(u32), stream);
    k_cand<<<CAND_GRID, CAND_THREADS, 0, stream>>>(x, candKey, candIdx, cnt, hist1p);
    k_mid<<<1, 1024, 0, stream>>>(candKey, hist1p, cnt, sufG);
    k_collect<<<COLL_GRID, 256, 0, stream>>>(candKey, candIdx, cnt, sufG, binCur, sel, eqI);
    k_binrank<<<H1_BINS + 1, 256, 0, stream>>>(sel, eqI, cnt, sufG, boxes,
                                               rboxes, rvals, rlabel, out);
    k_nms<<<80, 256, 0, stream>>>(rboxes, rvals, rlabel, out);
}